// Round 1
// baseline (173.914 us; speedup 1.0000x reference)
//
#include <hip/hip_runtime.h>

typedef float f4 __attribute__((ext_vector_type(4)));   // clang vector: NT-load legal

// ---------- helpers ----------
__device__ __forceinline__ float readlane_f(float v, int l) {
    return __int_as_float(__builtin_amdgcn_readlane(__float_as_int(v), l));
}

// ---------- kernel 1: conv 9x9 VALID + bias + relu -> XT f32 [12800][64] ----------
// x: [64,1,28,28] f32 ; conv_w: [32,1,9,9] f32 ; conv_b: [32] f32
// v2: block = (pb, c) covers one 40-p strip of one channel for ALL 64 batch images.
//   - LDS stages the 10 needed image rows per image: xs[64][281] (281 mod 32 = 25,
//     gcd(25,32)=1 -> lane-stride reads are 2 lanes/bank = conflict-free).
//   - thread = (psub = t>>6, b = t&63); per iteration p = pb*40 + i*4 + psub so the
//     block's 256 stores land at XT base + i*256 + t : fully contiguous 1KB lines.
//     (old version: one b per block -> 4B stores stride 256B -> partial-line RMW.)
//   - weights block-uniform (c = blockIdx.y) -> SGPR-resident.
// Blocks 0..15 also zero the 4096-float S1 accumulator.
__global__ __launch_bounds__(256) void conv_kernel(
    const float* __restrict__ X, const float* __restrict__ CW, const float* __restrict__ CB,
    float* __restrict__ XT, float* __restrict__ S1acc)
{
    int pb = blockIdx.x;             // 0..9  : 40-p strip
    int c  = blockIdx.y;             // 0..31 : channel
    int t  = threadIdx.x;
    int bid = blockIdx.y * 10 + blockIdx.x;
    if (bid < 16) S1acc[bid * 256 + t] = 0.0f;

    // stage rows [pb*2 .. pb*2+9] of every image: 280 consecutive floats / image
    __shared__ float xs[64][281];
    int py0 = pb * 2;
    {
        int b = t >> 2, q = t & 3;                       // 4 threads per image
        const f4* src = reinterpret_cast<const f4*>(X + b * 784 + py0 * 28);
        #pragma unroll
        for (int i = 0; i < 18; ++i) {
            int idx4 = q + 4 * i;                        // f4 index, 70 per image
            if (idx4 < 70) {
                f4 v = src[idx4];
                float* d = &xs[b][idx4 * 4];
                d[0] = v.x; d[1] = v.y; d[2] = v.z; d[3] = v.w;
            }
        }
    }
    __syncthreads();

    float bias = CB[c];
    const float* wcg = CW + c * 81;
    float w[81];                     // block-uniform -> compiler scalarizes to SGPRs
    #pragma unroll
    for (int i = 0; i < 81; ++i) w[i] = wcg[i];

    int psub = t >> 6, b = t & 63;
    size_t base = (size_t)(c * 400 + pb * 40) * 64;
    #pragma unroll
    for (int i = 0; i < 10; ++i) {
        int p  = pb * 40 + i * 4 + psub;
        int py = p / 20, px = p - py * 20;
        int pyr = py - py0;                              // 0 or 1
        float acc = bias;
        #pragma unroll
        for (int dy = 0; dy < 9; ++dy) {
            const float* xr = &xs[b][(pyr + dy) * 28 + px];
            #pragma unroll
            for (int dx = 0; dx < 9; ++dx)
                acc = fmaf(xr[dx], w[dy * 9 + dx], acc);
        }
        // addr = base + i*256 + psub*64 + b = base + i*256 + t  -> contiguous
        XT[base + (size_t)i * 256 + (size_t)psub * 64 + b] = acc > 0.f ? acc : 0.f;
    }
}

// ---------- kernel 2: the big W1 stream ----------
// s1[b,j,m] += sum_k xf[b,k] * (sum_c W1[j,k,m,c])
// v2: grid (100, 8), 512 thr = 8 waves, 128 k/block (16 k/wave).
//   halves block count, XT re-reads, and atomicAdd count (now 1 atomic/thread).
// One wave per k-row: lane loads float4 (16B, non-temporal) -> whole 1KB row.
// unroll 8: 8 NT loads in flight per wave; BW-bound (floor ~15.2 us @ 6.9 TB/s).
__global__ __launch_bounds__(512) void primary_kernel(
    const float* __restrict__ W1, const float* __restrict__ XT, float* __restrict__ S1acc)
{
    int kb = blockIdx.x;
    int j  = blockIdx.y;
    int t = threadIdx.x;
    int wave = t >> 6, lane = t & 63;
    int k0 = kb * 128 + wave * 16;
    const f4* Wp = reinterpret_cast<const f4*>(W1) + (size_t)j * 819200
                   + (size_t)k0 * 64 + lane;
    const float* Xp = XT + (size_t)k0 * 64 + lane;

    float acc[8] = {0.f,0.f,0.f,0.f,0.f,0.f,0.f,0.f};
    #pragma unroll 8
    for (int kk = 0; kk < 16; ++kk) {
        f4 w = __builtin_nontemporal_load(Wp); Wp += 64;   // stream-once: bypass L2
        float xv = *Xp; Xp += 64;                          // L2-resident, coalesced
        float s = (w.x + w.y) + (w.z + w.w);
        // reduce across the 8 lanes sharing this m (lane>>3 group)
        s += __shfl_xor(s, 1);
        s += __shfl_xor(s, 2);
        s += __shfl_xor(s, 4);
        #pragma unroll
        for (int m = 0; m < 8; ++m)
            acc[m] = fmaf(xv, readlane_f(s, m * 8), acc[m]);
    }

    __shared__ float red[8][64][9];     // +1 pad: conflict-free stride 9
    #pragma unroll
    for (int m = 0; m < 8; ++m) red[wave][lane][m] = acc[m];
    __syncthreads();
    {
        int bb = t >> 3, m = t & 7;     // t in [0,512) covers all (b,m) exactly once
        float v = red[0][bb][m] + red[1][bb][m] + red[2][bb][m] + red[3][bb][m]
                + red[4][bb][m] + red[5][bb][m] + red[6][bb][m] + red[7][bb][m];
        atomicAdd(&S1acc[(bb * 8 + j) * 8 + m], v);
    }
}

// ---------- kernel 3: squash v1, u2 transform, 3-iter routing, output ----------
// one block per batch element b
__global__ __launch_bounds__(256) void routing_kernel(
    const float* __restrict__ W2, const float* __restrict__ S1acc,
    float* __restrict__ OUT)
{
    int b = blockIdx.x;
    int t = threadIdx.x;
    __shared__ float v1[64];        // [k=8][c=8]
    __shared__ float u2[10][8][16];
    __shared__ float blog[10][8];
    __shared__ float cw[10][8];
    __shared__ float sv[10][16];
    __shared__ float vv[10][16];
    __shared__ float fac[16];

    if (t < 64) v1[t] = S1acc[b * 64 + t] * 0.125f;   // softmax(0) over 8 caps = 1/8
    if (t >= 64 && t < 144) { int q = t - 64; blog[q >> 3][q & 7] = 0.f; }
    __syncthreads();
    if (t < 8) {   // squash per primary capsule: |s|/(1+|s|^2) * s
        float n2 = 0.f;
        #pragma unroll
        for (int m = 0; m < 8; ++m) { float x = v1[t * 8 + m]; n2 = fmaf(x, x, n2); }
        float n = sqrtf(n2);
        fac[t] = n / (1.f + n2);
    }
    __syncthreads();
    if (t < 64) v1[t] *= fac[t >> 3];
    __syncthreads();

    // u2[j][k][m] = sum_c W2[j,k,m,c] * v1[k][c]
    for (int idx = t; idx < 1280; idx += 256) {
        int j = idx >> 7;
        int r = idx & 127;
        int k = r >> 4, m = r & 15;
        const float* wp = W2 + idx * 8;   // [j][k][m][c] contiguous, idx == (j*8+k)*16+m
        float a = 0.f;
        #pragma unroll
        for (int c = 0; c < 8; ++c) a = fmaf(wp[c], v1[k * 8 + c], a);
        u2[j][k][m] = a;
    }
    __syncthreads();

    for (int it = 0; it < 3; ++it) {
        if (t < 8) {   // softmax over 10 classes for k = t
            float mx = -1e30f;
            #pragma unroll
            for (int j = 0; j < 10; ++j) mx = fmaxf(mx, blog[j][t]);
            float e[10], se = 0.f;
            #pragma unroll
            for (int j = 0; j < 10; ++j) { e[j] = expf(blog[j][t] - mx); se += e[j]; }
            float inv = 1.f / se;
            #pragma unroll
            for (int j = 0; j < 10; ++j) cw[j][t] = e[j] * inv;
        }
        __syncthreads();
        if (t < 160) {   // s[j][m] = sum_k c[j][k] * u2[j][k][m]
            int j = t >> 4, m = t & 15;
            float a = 0.f;
            #pragma unroll
            for (int k = 0; k < 8; ++k) a = fmaf(cw[j][k], u2[j][k][m], a);
            sv[j][m] = a;
        }
        __syncthreads();
        if (t < 10) {    // squash factor per class
            float n2 = 0.f;
            #pragma unroll
            for (int m = 0; m < 16; ++m) { float x = sv[t][m]; n2 = fmaf(x, x, n2); }
            float n = sqrtf(n2);
            fac[t] = n / (1.f + n2);
        }
        __syncthreads();
        if (t < 160) { int j = t >> 4, m = t & 15; vv[j][m] = sv[j][m] * fac[j]; }
        __syncthreads();
        if (it < 2) {
            if (t < 80) {   // b[j][k] += sum_m u2[j][k][m] * v[j][m]
                int j = t >> 3, k = t & 7;
                float d = 0.f;
                #pragma unroll
                for (int m = 0; m < 16; ++m) d = fmaf(u2[j][k][m], vv[j][m], d);
                blog[j][k] += d;
            }
            __syncthreads();
        }
    }
    if (t < 160) OUT[b * 160 + t] = vv[t >> 4][t & 15];
}

// ---------- launch ----------
extern "C" void kernel_launch(void* const* d_in, const int* in_sizes, int n_in,
                              void* d_out, int out_size, void* d_ws, size_t ws_size,
                              hipStream_t stream) {
    const float* X  = (const float*)d_in[0];
    const float* CW = (const float*)d_in[1];
    const float* CB = (const float*)d_in[2];
    const float* W1 = (const float*)d_in[3];
    const float* W2 = (const float*)d_in[4];
    float* S1 = (float*)d_ws;                         // 4096 f32 = 16 KB
    float* XT = (float*)((char*)d_ws + 16384);        // 819200 f32 = 3.2 MB
    float* OUT = (float*)d_out;

    conv_kernel<<<dim3(10, 32), 256, 0, stream>>>(X, CW, CB, XT, S1);
    primary_kernel<<<dim3(100, 8), 512, 0, stream>>>(W1, XT, S1);
    routing_kernel<<<64, 256, 0, stream>>>(W2, S1, OUT);
}

// Round 3
// 168.648 us; speedup vs baseline: 1.0312x; 1.0312x over previous
//
#include <hip/hip_runtime.h>

typedef float f4 __attribute__((ext_vector_type(4)));   // clang vector: NT-load legal

// ---------- helpers ----------
__device__ __forceinline__ float readlane_f(float v, int l) {
    return __int_as_float(__builtin_amdgcn_readlane(__float_as_int(v), l));
}

// ---------- kernel 1: FUSED conv + W1 stream ----------
// 256 blocks x 512 thr (1 block/CU, exactly balanced).
// block i owns k rows [i*50, i*50+50): c = i>>3, p0 = (i&7)*50.
//  Phase A (conv -> LDS, no global intermediate):
//    stage the 11 needed image rows (308 f32) for 32 images at a time
//    (xs 39.6 KB), convolve 50 p x 64 b into xt[50][64] (12.8 KB LDS).
//    Weights block-uniform (c from blockIdx) -> SGPR-resident.
//  Phase B (stream): wave w owns j=w. Lane loads f4 of W1[j,k] (NT, 1KB/row/wave),
//    3x shfl_xor reduces the 8-lane c-group -> Wsum[m]; acc[m] += xt[k][lane=b]*Wsum.
//    Each wave's acc IS the final partial for (j=w, b, m): no cross-wave reduce,
//    no atomics. Coalesced f4x2 store to S1P[i][j][b][m] (4 MB partials).
// BW floor: 104.9 MB W1 @ ~6.9 TB/s = 15.2 us.
__global__ __launch_bounds__(512) void fused_kernel(
    const float* __restrict__ X, const float* __restrict__ CW, const float* __restrict__ CB,
    const float* __restrict__ W1, float* __restrict__ S1P)
{
    int i = blockIdx.x;
    int c = i >> 3, p0 = (i & 7) * 50;
    int t = threadIdx.x;
    int wave = t >> 6, lane = t & 63;

    __shared__ float xs[32][309];   // 11 rows x 28 = 308 (+1 slot), 32 images/pass
    __shared__ float xt[50][64];    // conv output: [p_local][b]

    int py0 = p0 / 20;              // 50-p strip spans output rows py0..py0+2 -> input rows py0..py0+10

    float bias = CB[c];
    const float* wcg = CW + c * 81;
    float w[81];                    // block-uniform -> compiler scalarizes to SGPRs
    #pragma unroll
    for (int q = 0; q < 81; ++q) w[q] = wcg[q];

    // ---- Phase A: conv in two 32-image passes (keeps LDS = 52.4 KB) ----
    for (int h = 0; h < 2; ++h) {
        {   // stage 32 x 308 floats = 77 f4 per image, 16 thr/image
            int b = t >> 4, q = t & 15;
            const f4* src = reinterpret_cast<const f4*>(X + (size_t)(b + 32 * h) * 784 + py0 * 28);
            #pragma unroll
            for (int it2 = 0; it2 < 5; ++it2) {
                int idx4 = q + 16 * it2;
                if (idx4 < 77) {
                    f4 v = src[idx4];
                    float* d = &xs[b][idx4 * 4];
                    d[0] = v.x; d[1] = v.y; d[2] = v.z; d[3] = v.w;
                }
            }
        }
        __syncthreads();
        {   // thread = (psub = t>>5 in 0..15, b = t&31); p_local = psub, +16, ...
            int psub = t >> 5, b = t & 31;
            for (int pl = psub; pl < 50; pl += 16) {
                int p = p0 + pl;
                int py = p / 20, px = p - py * 20;
                const float* xrow = &xs[b][(py - py0) * 28 + px];
                float acc = bias;
                #pragma unroll
                for (int dy = 0; dy < 9; ++dy)
                    #pragma unroll
                    for (int dx = 0; dx < 9; ++dx)
                        acc = fmaf(xrow[dy * 28 + dx], w[dy * 9 + dx], acc);
                xt[pl][b + 32 * h] = acc > 0.f ? acc : 0.f;   // relu
            }
        }
        __syncthreads();   // protects xs overwrite (h=0) and xt completeness (h=1)
    }

    // ---- Phase B: stream W1[j=wave, k0..k0+49], 1 KB row per wave-load ----
    int k0 = c * 400 + p0;
    const f4* Wp = reinterpret_cast<const f4*>(W1) + (size_t)wave * 819200
                   + (size_t)k0 * 64 + lane;
    float acc[8] = {0.f,0.f,0.f,0.f,0.f,0.f,0.f,0.f};
    #pragma unroll 10
    for (int kk = 0; kk < 50; ++kk) {
        f4 wv = __builtin_nontemporal_load(Wp); Wp += 64;   // stream-once: bypass L2
        float xv = xt[kk][lane];                            // LDS, 2-way = free
        float s = (wv.x + wv.y) + (wv.z + wv.w);
        s += __shfl_xor(s, 1);
        s += __shfl_xor(s, 2);
        s += __shfl_xor(s, 4);                              // Wsum[m] in lane group m
        #pragma unroll
        for (int m = 0; m < 8; ++m)
            acc[m] = fmaf(xv, readlane_f(s, m * 8), acc[m]);
    }

    // final partial for (j=wave, b=lane, m): coalesced 2x f4 store
    float* dst = S1P + ((((size_t)i * 8 + wave) * 64 + lane) * 8);
    f4 lo = {acc[0], acc[1], acc[2], acc[3]};
    f4 hi = {acc[4], acc[5], acc[6], acc[7]};
    reinterpret_cast<f4*>(dst)[0] = lo;
    reinterpret_cast<f4*>(dst)[1] = hi;
}

// ---------- kernel 2: partial-reduce + squash v1 + u2 + 3-iter routing ----------
// one block per batch element b; prologue sums the 256 block-partials.
__global__ __launch_bounds__(256) void routing_kernel(
    const float* __restrict__ W2, const float* __restrict__ S1P,
    float* __restrict__ OUT)
{
    int b = blockIdx.x;
    int t = threadIdx.x;
    __shared__ float part[64][4];   // [j*8+m][r]
    __shared__ float v1[64];        // [k=8][c=8]
    __shared__ float u2[10][8][16];
    __shared__ float blog[10][8];
    __shared__ float cw[10][8];
    __shared__ float sv[10][16];
    __shared__ float vv[10][16];
    __shared__ float fac[16];

    {   // s1[b][j][m] = sum_i S1P[i][j][b][m]; thread = (jm = t>>2, r = t&3)
        int jm = t >> 2, r = t & 3;
        int j = jm >> 3, m = jm & 7;
        size_t base = (size_t)j * 512 + (size_t)b * 8 + m;
        float ssum = 0.f;
        #pragma unroll 16
        for (int ii = r; ii < 256; ii += 4)
            ssum += S1P[base + (size_t)ii * 4096];   // independent -> deep in flight
        part[jm][r] = ssum;
    }
    __syncthreads();
    if (t < 64) v1[t] = (part[t][0] + part[t][1] + part[t][2] + part[t][3]) * 0.125f;
    if (t >= 64 && t < 144) { int q = t - 64; blog[q >> 3][q & 7] = 0.f; }
    __syncthreads();
    if (t < 8) {   // squash per primary capsule: |s|/(1+|s|^2) * s
        float n2 = 0.f;
        #pragma unroll
        for (int m = 0; m < 8; ++m) { float x = v1[t * 8 + m]; n2 = fmaf(x, x, n2); }
        float n = sqrtf(n2);
        fac[t] = n / (1.f + n2);
    }
    __syncthreads();
    if (t < 64) v1[t] *= fac[t >> 3];
    __syncthreads();

    // u2[j][k][m] = sum_c W2[j,k,m,c] * v1[k][c]
    for (int idx = t; idx < 1280; idx += 256) {
        int j = idx >> 7;
        int r = idx & 127;
        int k = r >> 4, m = r & 15;
        const float* wp = W2 + idx * 8;   // [j][k][m][c] contiguous
        float a = 0.f;
        #pragma unroll
        for (int cc = 0; cc < 8; ++cc) a = fmaf(wp[cc], v1[k * 8 + cc], a);
        u2[j][k][m] = a;
    }
    __syncthreads();

    for (int it = 0; it < 3; ++it) {
        if (t < 8) {   // softmax over 10 classes for k = t
            float mx = -1e30f;
            #pragma unroll
            for (int j = 0; j < 10; ++j) mx = fmaxf(mx, blog[j][t]);
            float e[10], se = 0.f;
            #pragma unroll
            for (int j = 0; j < 10; ++j) { e[j] = expf(blog[j][t] - mx); se += e[j]; }
            float inv = 1.f / se;
            #pragma unroll
            for (int j = 0; j < 10; ++j) cw[j][t] = e[j] * inv;
        }
        __syncthreads();
        if (t < 160) {   // s[j][m] = sum_k c[j][k] * u2[j][k][m]
            int j = t >> 4, m = t & 15;
            float a = 0.f;
            #pragma unroll
            for (int k = 0; k < 8; ++k) a = fmaf(cw[j][k], u2[j][k][m], a);
            sv[j][m] = a;
        }
        __syncthreads();
        if (t < 10) {    // squash factor per class
            float n2 = 0.f;
            #pragma unroll
            for (int m = 0; m < 16; ++m) { float x = sv[t][m]; n2 = fmaf(x, x, n2); }
            float n = sqrtf(n2);
            fac[t] = n / (1.f + n2);
        }
        __syncthreads();
        if (t < 160) { int j = t >> 4, m = t & 15; vv[j][m] = sv[j][m] * fac[j]; }
        __syncthreads();
        if (it < 2) {
            if (t < 80) {   // b[j][k] += sum_m u2[j][k][m] * v[j][m]
                int j = t >> 3, k = t & 7;
                float d = 0.f;
                #pragma unroll
                for (int m = 0; m < 16; ++m) d = fmaf(u2[j][k][m], vv[j][m], d);
                blog[j][k] += d;
            }
            __syncthreads();
        }
    }
    if (t < 160) OUT[b * 160 + t] = vv[t >> 4][t & 15];
}

// ---------- launch ----------
extern "C" void kernel_launch(void* const* d_in, const int* in_sizes, int n_in,
                              void* d_out, int out_size, void* d_ws, size_t ws_size,
                              hipStream_t stream) {
    const float* X  = (const float*)d_in[0];
    const float* CW = (const float*)d_in[1];
    const float* CB = (const float*)d_in[2];
    const float* W1 = (const float*)d_in[3];
    const float* W2 = (const float*)d_in[4];
    float* S1P = (float*)d_ws;                        // 256*4096 f32 = 4 MB partials
    float* OUT = (float*)d_out;

    fused_kernel<<<256, 512, 0, stream>>>(X, CW, CB, W1, S1P);
    routing_kernel<<<64, 256, 0, stream>>>(W2, S1P, OUT);
}

// Round 6
// 165.508 us; speedup vs baseline: 1.0508x; 1.0190x over previous
//
#include <hip/hip_runtime.h>

typedef float f4 __attribute__((ext_vector_type(4)));   // clang vector: NT-load legal

// ---------- helpers ----------
__device__ __forceinline__ float readlane_f(float v, int l) {
    return __int_as_float(__builtin_amdgcn_readlane(__float_as_int(v), l));
}

// lgkm-only workgroup barrier: syncs LDS producer->consumer WITHOUT the
// vmcnt(0) drain __syncthreads() emits, so outstanding global (W1 prefetch)
// loads stay in flight across conv.  All cross-thread deps in this kernel go
// through LDS (ds_write -> lgkmcnt(0) -> s_barrier -> ds_read), which this
// covers; the staging ds_writes' own vmcnt deps are auto-inserted by the
// compiler.  "memory" clobber blocks IR-level motion of LDS ops across it.
__device__ __forceinline__ void barrier_lds() {
    asm volatile("s_waitcnt lgkmcnt(0)\n\ts_barrier" ::: "memory");
}

// ---------- kernel 1: FUSED conv + W1 stream ----------
// 256 blocks x 512 thr (1 block/CU).  Block i owns k rows [i*50, i*50+50):
// c = i>>3, p0 = (i&7)*50 (50-p strip spans 3 output rows -> 11 input rows).
//  - W1 prefetch: 10 rows (per wave) NT-loaded into regs BEFORE conv; with
//    lgkm-only barriers they remain in flight while Phase A runs -> HBM busy
//    from cycle 0.
//  - Phase A: stage all 64 images' 11 rows (xs 77.2 KB) in one pass, conv
//    50 p x 64 b into xt[50][64] (12.8 KB).  Weights block-uniform -> SGPRs.
//  - Phase B: wave w owns j=w; lane loads f4 of W1[j,k] (NT, 1KB/row/wave),
//    3x shfl_xor reduces the 8-lane c-group -> Wsum[m];
//    acc[m] += xt[k][lane=b] * Wsum[m].  No cross-wave reduce, no atomics.
//  - Partial store layout [i][b][j][m]: per-b rows are 256B contiguous so
//    the routing prologue reads full lines with f4 loads (no overfetch).
// BW floor: 104.9 MB W1 @ ~6.9 TB/s = 15.2 us.
__global__ __launch_bounds__(512) void fused_kernel(
    const float* __restrict__ X, const float* __restrict__ CW, const float* __restrict__ CB,
    const float* __restrict__ W1, float* __restrict__ S1P)
{
    int i = blockIdx.x;
    int c = i >> 3, p0 = (i & 7) * 50;
    int t = threadIdx.x;
    int wave = t >> 6, lane = t & 63;

    __shared__ float xs[64][309];   // 11 rows x 28 = 308 (+1 pad -> stride 309, gcd(309%32=21,32)=1)
    __shared__ float xt[50][64];    // conv output: [p_local][b]

    int py0 = p0 / 20;

    // ---- W1 prefetch: rows k0..k0+9 for j = wave (W1 is read-only: safe
    //      to keep outstanding across barriers) ----
    int k0 = c * 400 + p0;
    const f4* Wp = reinterpret_cast<const f4*>(W1) + (size_t)wave * 819200
                   + (size_t)k0 * 64 + lane;
    f4 pre[10];
    #pragma unroll
    for (int q = 0; q < 10; ++q)
        pre[q] = __builtin_nontemporal_load(Wp + (size_t)q * 64);

    float bias = CB[c];
    const float* wcg = CW + c * 81;
    float w[81];                    // block-uniform -> compiler scalarizes to SGPRs
    #pragma unroll
    for (int q = 0; q < 81; ++q) w[q] = wcg[q];

    // ---- Phase A: stage 64 images x 308 floats (77 f4 each), 8 thr/image ----
    {
        int b = t >> 3, q = t & 7;
        const f4* src = reinterpret_cast<const f4*>(X + (size_t)b * 784 + py0 * 28);
        #pragma unroll
        for (int s = 0; s < 10; ++s) {
            int idx4 = q + 8 * s;
            if (idx4 < 77) {
                f4 v = src[idx4];
                float* d = &xs[b][idx4 * 4];
                d[0] = v.x; d[1] = v.y; d[2] = v.z; d[3] = v.w;
            }
        }
    }
    barrier_lds();

    // ---- conv: thread (psub = wave, b = lane); pl = psub + 8s (wave-uniform trip) ----
    {
        int psub = wave, b = lane;
        for (int pl = psub; pl < 50; pl += 8) {
            int p = p0 + pl;
            int py = p / 20, px = p - py * 20;
            const float* xrow = &xs[b][(py - py0) * 28 + px];
            float acc = bias;
            #pragma unroll
            for (int dy = 0; dy < 9; ++dy)
                #pragma unroll
                for (int dx = 0; dx < 9; ++dx)
                    acc = fmaf(xrow[dy * 28 + dx], w[dy * 9 + dx], acc);
            xt[pl][b] = acc > 0.f ? acc : 0.f;   // relu
        }
    }
    barrier_lds();

    // ---- Phase B: consume prefetch, then stream rows 10..49 ----
    float acc[8] = {0.f,0.f,0.f,0.f,0.f,0.f,0.f,0.f};
    #pragma unroll
    for (int kk = 0; kk < 10; ++kk) {
        f4 wv = pre[kk];
        float xv = xt[kk][lane];
        float s = (wv.x + wv.y) + (wv.z + wv.w);
        s += __shfl_xor(s, 1);
        s += __shfl_xor(s, 2);
        s += __shfl_xor(s, 4);                              // Wsum[m] in lane group m
        #pragma unroll
        for (int m = 0; m < 8; ++m)
            acc[m] = fmaf(xv, readlane_f(s, m * 8), acc[m]);
    }
    Wp += (size_t)10 * 64;
    #pragma unroll 10
    for (int kk = 10; kk < 50; ++kk) {
        f4 wv = __builtin_nontemporal_load(Wp); Wp += 64;   // stream-once: bypass L2
        float xv = xt[kk][lane];
        float s = (wv.x + wv.y) + (wv.z + wv.w);
        s += __shfl_xor(s, 1);
        s += __shfl_xor(s, 2);
        s += __shfl_xor(s, 4);
        #pragma unroll
        for (int m = 0; m < 8; ++m)
            acc[m] = fmaf(xv, readlane_f(s, m * 8), acc[m]);
    }

    // final partial for (b=lane, j=wave, m): layout [i][b][j][m]
    float* dst = S1P + (((size_t)i * 64 + lane) * 8 + wave) * 8;
    f4 lo = {acc[0], acc[1], acc[2], acc[3]};
    f4 hi = {acc[4], acc[5], acc[6], acc[7]};
    reinterpret_cast<f4*>(dst)[0] = lo;
    reinterpret_cast<f4*>(dst)[1] = hi;
}

// ---------- kernel 2: partial-reduce + squash v1 + u2 + 3-iter routing ----------
// one block per batch element b; prologue sums the 256 block-partials.
// Layout [i][b][j][m]: block b reads 256 contiguous 256B rows (f4, full lines).
__global__ __launch_bounds__(256) void routing_kernel(
    const float* __restrict__ W2, const float* __restrict__ S1P,
    float* __restrict__ OUT)
{
    int b = blockIdx.x;
    int t = threadIdx.x;
    __shared__ float part[16][64];  // [r = i mod 16][j*8+m]
    __shared__ float v1[64];        // [k=8][c=8]
    __shared__ float u2[10][8][16];
    __shared__ float blog[10][8];
    __shared__ float cw[10][8];
    __shared__ float sv[10][16];
    __shared__ float vv[10][16];
    __shared__ float fac[16];

    {   // thread (q = t&15: f4 within the 64-float row, r = t>>4: i mod 16)
        int q = t & 15, r = t >> 4;
        const f4* base = reinterpret_cast<const f4*>(S1P) + ((size_t)r * 64 + b) * 16 + q;
        f4 a = {0.f, 0.f, 0.f, 0.f};
        #pragma unroll
        for (int s = 0; s < 16; ++s)
            a += base[(size_t)s * 16384];   // i += 16 -> 16*4096 floats = 16384 f4
        part[r][q * 4 + 0] = a.x;
        part[r][q * 4 + 1] = a.y;
        part[r][q * 4 + 2] = a.z;
        part[r][q * 4 + 3] = a.w;
    }
    __syncthreads();
    if (t < 64) {
        float v = 0.f;
        #pragma unroll
        for (int r = 0; r < 16; ++r) v += part[r][t];
        v1[t] = v * 0.125f;             // softmax(0) over 8 caps = 1/8
    }
    if (t >= 64 && t < 144) { int q = t - 64; blog[q >> 3][q & 7] = 0.f; }
    __syncthreads();
    if (t < 8) {   // squash per primary capsule: |s|/(1+|s|^2) * s
        float n2 = 0.f;
        #pragma unroll
        for (int m = 0; m < 8; ++m) { float x = v1[t * 8 + m]; n2 = fmaf(x, x, n2); }
        float n = sqrtf(n2);
        fac[t] = n / (1.f + n2);
    }
    __syncthreads();
    if (t < 64) v1[t] *= fac[t >> 3];
    __syncthreads();

    // u2[j][k][m] = sum_c W2[j,k,m,c] * v1[k][c]
    for (int idx = t; idx < 1280; idx += 256) {
        int j = idx >> 7;
        int r = idx & 127;
        int k = r >> 4, m = r & 15;
        const float* wp = W2 + idx * 8;   // [j][k][m][c] contiguous
        float a = 0.f;
        #pragma unroll
        for (int cc = 0; cc < 8; ++cc) a = fmaf(wp[cc], v1[k * 8 + cc], a);
        u2[j][k][m] = a;
    }
    __syncthreads();

    for (int it = 0; it < 3; ++it) {
        if (t < 8) {   // softmax over 10 classes for k = t
            float mx = -1e30f;
            #pragma unroll
            for (int j = 0; j < 10; ++j) mx = fmaxf(mx, blog[j][t]);
            float e[10], se = 0.f;
            #pragma unroll
            for (int j = 0; j < 10; ++j) { e[j] = expf(blog[j][t] - mx); se += e[j]; }
            float inv = 1.f / se;
            #pragma unroll
            for (int j = 0; j < 10; ++j) cw[j][t] = e[j] * inv;
        }
        __syncthreads();
        if (t < 160) {   // s[j][m] = sum_k c[j][k] * u2[j][k][m]
            int j = t >> 4, m = t & 15;
            float a = 0.f;
            #pragma unroll
            for (int k = 0; k < 8; ++k) a = fmaf(cw[j][k], u2[j][k][m], a);
            sv[j][m] = a;
        }
        __syncthreads();
        if (t < 10) {    // squash factor per class
            float n2 = 0.f;
            #pragma unroll
            for (int m = 0; m < 16; ++m) { float x = sv[t][m]; n2 = fmaf(x, x, n2); }
            float n = sqrtf(n2);
            fac[t] = n / (1.f + n2);
        }
        __syncthreads();
        if (t < 160) { int j = t >> 4, m = t & 15; vv[j][m] = sv[j][m] * fac[j]; }
        __syncthreads();
        if (it < 2) {
            if (t < 80) {   // b[j][k] += sum_m u2[j][k][m] * v[j][m]
                int j = t >> 3, k = t & 7;
                float d = 0.f;
                #pragma unroll
                for (int m = 0; m < 16; ++m) d = fmaf(u2[j][k][m], vv[j][m], d);
                blog[j][k] += d;
            }
            __syncthreads();
        }
    }
    if (t < 160) OUT[b * 160 + t] = vv[t >> 4][t & 15];
}

// ---------- launch ----------
extern "C" void kernel_launch(void* const* d_in, const int* in_sizes, int n_in,
                              void* d_out, int out_size, void* d_ws, size_t ws_size,
                              hipStream_t stream) {
    const float* X  = (const float*)d_in[0];
    const float* CW = (const float*)d_in[1];
    const float* CB = (const float*)d_in[2];
    const float* W1 = (const float*)d_in[3];
    const float* W2 = (const float*)d_in[4];
    float* S1P = (float*)d_ws;                        // 256*4096 f32 = 4 MB partials
    float* OUT = (float*)d_out;

    fused_kernel<<<256, 512, 0, stream>>>(X, CW, CB, W1, S1P);
    routing_kernel<<<64, 256, 0, stream>>>(W2, S1P, OUT);
}